// Round 11
// baseline (451.123 us; speedup 1.0000x reference)
//
#include <hip/hip_runtime.h>
#include <hip/hip_bf16.h>

// Sizes (fixed by the reference): B=4096, D=1024, H1=2048, H2=1024, C=64, T=20
#define B_   4096
#define D_   1024
#define H1_  2048
#define H2_  1024
#define C_   64

typedef double d4 __attribute__((ext_vector_type(4)));

#if defined(__has_builtin)
#  if __has_builtin(__builtin_amdgcn_mfma_f64_16x16x4f64)
#    define MFMA64(A, B, C) __builtin_amdgcn_mfma_f64_16x16x4f64((A), (B), (C), 0, 0, 0)
#    define HAVE_MFMA64 1
#  elif __has_builtin(__builtin_amdgcn_mfma_f64_16x16x4_f64)
#    define MFMA64(A, B, C) __builtin_amdgcn_mfma_f64_16x16x4_f64((A), (B), (C), 0, 0, 0)
#    define HAVE_MFMA64 1
#  endif
#endif

// ---------------------------------------------------------------------------
// Probe: discover v_mfma_f64_16x16x4 D-fragment layout at runtime.
// ---------------------------------------------------------------------------
__global__ void k_probe(int* flag) {
#if defined(HAVE_MFMA64)
    int lane = threadIdx.x & 63;
    int lr = lane & 15, lk = lane >> 4;
    double a  = (double)(5 * lr + 3 * lk + 1);    // A[r][k] = 5r+3k+1
    double bb = (double)(11 * lk + 2 * lr + 2);   // B[k][c] = 11k+2c+2
    d4 c = {0.0, 0.0, 0.0, 0.0};
    c = MFMA64(a, bb, c);
    int okm[4] = {1, 1, 1, 1};
#pragma unroll
    for (int j = 0; j < 4; ++j) {
        double e1 = 0, e2 = 0, e3 = 0, e4 = 0;
        for (int k = 0; k < 4; ++k) {
            e1 += (double)(5 * (4 * lk + j) + 3 * k + 1) * (double)(11 * k + 2 * lr + 2);
            e2 += (double)(5 * lr + 3 * k + 1) * (double)(11 * k + 2 * (4 * lk + j) + 2);
            e3 += (double)(5 * (lk + 4 * j) + 3 * k + 1) * (double)(11 * k + 2 * lr + 2);
            e4 += (double)(5 * lr + 3 * k + 1) * (double)(11 * k + 2 * (lk + 4 * j) + 2);
        }
        if (c[j] != e1) okm[0] = 0;
        if (c[j] != e2) okm[1] = 0;
        if (c[j] != e3) okm[2] = 0;
        if (c[j] != e4) okm[3] = 0;
    }
    int f = 0;
    for (int m = 3; m >= 0; --m) {
        unsigned long long all = __ballot(okm[m] != 0);
        if (all == ~0ULL) f = m + 1;
    }
    if (lane == 0) flag[0] = f;
#else
    if ((threadIdx.x & 63) == 0) flag[0] = 0;
#endif
}

// ---------------------------------------------------------------------------
// Transpose: out[c][r] = in[r][c]   (f32, 32x32 LDS tiles)
// ---------------------------------------------------------------------------
__global__ __launch_bounds__(256) void k_transpose(const float* __restrict__ in,
                                                   float* __restrict__ out,
                                                   int R, int C) {
    __shared__ float t[32][33];
    int c0 = blockIdx.x * 32;
    int r0 = blockIdx.y * 32;
    int lx = threadIdx.x;
    int ly = threadIdx.y;
#pragma unroll
    for (int q = 0; q < 4; ++q) {
        int rr = ly + 8 * q;
        t[rr][lx] = in[(size_t)(r0 + rr) * C + (c0 + lx)];
    }
    __syncthreads();
#pragma unroll
    for (int q = 0; q < 4; ++q) {
        int cc = ly + 8 * q;
        out[(size_t)(c0 + cc) * R + (r0 + lx)] = t[lx][cc];
    }
}

// ---------------------------------------------------------------------------
// f64 MFMA GEMM v6: tile 128x64, GBK=16, 512 thr (8 waves, wave-tile 32x32).
// Grid 32x32 = 1024 blocks = 4 blocks/CU -> up to 8 waves/SIMD: barrier
// drains of one block hide under MFMA of the other three.
// LDS f64 single-buffer: A stride 136 + 8*(k>>2), B stride 72 + 8*(k>>2)
// (phase-minimal bank access for 8B ops). k-order per output element
// identical to v5 (ascending 4-chunks) -> bit-identical, absmax 0.
// ---------------------------------------------------------------------------
#define GBM 128
#define GBN 64
#define GBK 16
#define ASZ64 2192   // AIDX64(15,127)+1
#define BSZ64 1168   // BIDX64(15,63)+1
__device__ __forceinline__ int AIDX64(int k, int r) {
    return k * 136 + ((k >> 2) << 3) + r;
}
__device__ __forceinline__ int BIDX64(int k, int r) {
    return k * 72 + ((k >> 2) << 3) + r;
}
__global__ __launch_bounds__(512, 8) void k_gemm_mfma(const float* __restrict__ x,
                                                      const float* __restrict__ W1,
                                                      const float* __restrict__ b1,
                                                      double* __restrict__ m1out,
                                                      const int* __restrict__ flag) {
#if defined(HAVE_MFMA64)
    int fm = flag[0];
    if (fm < 1 || fm > 4) return;
    __shared__ double As[ASZ64];   // 17.5 KB
    __shared__ double Bs[BSZ64];   //  9.3 KB   (26.9 KB total -> 4 blocks/CU)

    int tid = threadIdx.x;
    int m0 = blockIdx.x * GBM;
    int n0 = blockIdx.y * GBN;
    int w = tid >> 6, lane = tid & 63;
    int wr = w >> 1;        // 0..3 : 32-row band
    int wc = w & 1;         // 0..1 : 32-col band
    int lr = lane & 15, lk = lane >> 4;

    int srowA = tid >> 2;          // 0..127
    int gA    = tid & 3;           // k group 0,4,8,12
    int woffA = AIDX64(gA * 4, srowA);   // q adds 136

    int srowB = (tid & 255) >> 2;  // 0..63 (threads 0..255 stage B)
    int gB    = tid & 3;
    int woffB = BIDX64(gB * 4, srowB);   // q adds 72
    bool doB  = (tid < 256);

    const float* xrow = x  + (size_t)(m0 + srowA) * D_;
    const float* wrow = W1 + (size_t)(n0 + srowB) * D_;

    d4 acc[2][2];
#pragma unroll
    for (int i = 0; i < 2; ++i)
#pragma unroll
        for (int j = 0; j < 2; ++j) acc[i][j] = (d4){0.0, 0.0, 0.0, 0.0};

    for (int k0 = 0; k0 < D_; k0 += GBK) {
        float4 av = *(const float4*)&xrow[k0 + gA * 4];
        float4 bv;
        if (doB) bv = *(const float4*)&wrow[k0 + gB * 4];
        __syncthreads();   // all fragment reads of previous tile complete
        As[woffA +   0] = (double)av.x;
        As[woffA + 136] = (double)av.y;
        As[woffA + 272] = (double)av.z;
        As[woffA + 408] = (double)av.w;
        if (doB) {
            Bs[woffB +   0] = (double)bv.x;
            Bs[woffB +  72] = (double)bv.y;
            Bs[woffB + 144] = (double)bv.z;
            Bs[woffB + 216] = (double)bv.w;
        }
        __syncthreads();   // tile staged
#pragma unroll
        for (int kb = 0; kb < 4; ++kb) {
            int k = kb * 4 + lk;
            int abase = AIDX64(k, wr * 32 + lr);
            int bbase = BIDX64(k, wc * 32 + lr);
            double a[2], bfr[2];
#pragma unroll
            for (int i = 0; i < 2; ++i) a[i]   = As[abase + 16 * i];
#pragma unroll
            for (int j = 0; j < 2; ++j) bfr[j] = Bs[bbase + 16 * j];
#pragma unroll
            for (int i = 0; i < 2; ++i)
#pragma unroll
                for (int j = 0; j < 2; ++j)
                    acc[i][j] = MFMA64(a[i], bfr[j], acc[i][j]);
        }
    }

    // epilogue: D-mapping selected by fm
#pragma unroll
    for (int j = 0; j < 2; ++j)
#pragma unroll
        for (int i = 0; i < 2; ++i)
#pragma unroll
            for (int r = 0; r < 4; ++r) {
                int rin = (fm == 1) ? (4 * lk + r) : (fm == 2) ? lr
                        : (fm == 3) ? (lk + 4 * r) : lr;
                int cin = (fm == 1) ? lr : (fm == 2) ? (4 * lk + r)
                        : (fm == 3) ? lr : (lk + 4 * r);
                int row = m0 + wr * 32 + 16 * i + rin;
                int col = n0 + wc * 32 + 16 * j + cin;
                m1out[(size_t)row * H1_ + col] = acc[i][j][r] + (double)b1[col];
            }
#else
    (void)x; (void)W1; (void)b1; (void)m1out; (void)flag;
#endif
}

// ---------------------------------------------------------------------------
// Fallback VALU f64 GEMM (proven). Runs iff flag not in {1..4}.
// ---------------------------------------------------------------------------
#define BM 128
#define BN 128
#define BK 8
__global__ __launch_bounds__(256) void k_gemm1(const float* __restrict__ x,
                                               const float* __restrict__ W1,
                                               const float* __restrict__ b1,
                                               double* __restrict__ m1out,
                                               const int* __restrict__ flag) {
    int fm = flag[0];
    if (fm >= 1 && fm <= 4) return;
    __shared__ double As[BK][BM + 4];
    __shared__ double Bs[BK][BN + 4];

    int tid = threadIdx.x;
    int m0 = blockIdx.x * BM;
    int n0 = blockIdx.y * BN;
    int tx = tid & 15;
    int ty = tid >> 4;
    int lr = tid >> 1;
    int lk = (tid & 1) * 4;

    double acc[8][8] = {};

    for (int k0 = 0; k0 < D_; k0 += BK) {
        float4 av = *(const float4*)&x [(size_t)(m0 + lr) * D_ + k0 + lk];
        float4 bv = *(const float4*)&W1[(size_t)(n0 + lr) * D_ + k0 + lk];
        __syncthreads();
        As[lk + 0][lr] = (double)av.x;
        As[lk + 1][lr] = (double)av.y;
        As[lk + 2][lr] = (double)av.z;
        As[lk + 3][lr] = (double)av.w;
        Bs[lk + 0][lr] = (double)bv.x;
        Bs[lk + 1][lr] = (double)bv.y;
        Bs[lk + 2][lr] = (double)bv.z;
        Bs[lk + 3][lr] = (double)bv.w;
        __syncthreads();
#pragma unroll
        for (int kk = 0; kk < BK; ++kk) {
            double a[8], b[8];
#pragma unroll
            for (int i = 0; i < 8; ++i) a[i] = As[kk][tx + 16 * i];
#pragma unroll
            for (int j = 0; j < 8; ++j) b[j] = Bs[kk][ty + 16 * j];
#pragma unroll
            for (int i = 0; i < 8; ++i)
#pragma unroll
                for (int j = 0; j < 8; ++j)
                    acc[i][j] += a[i] * b[j];
        }
    }
#pragma unroll
    for (int j = 0; j < 8; ++j) {
        double bj = (double)b1[n0 + ty + 16 * j];
#pragma unroll
        for (int i = 0; i < 8; ++i) {
            m1out[(size_t)(m0 + tx + 16 * i) * H1_ + (n0 + ty + 16 * j)] =
                acc[i][j] + bj;
        }
    }
}

// ---------------------------------------------------------------------------
// Persistent per-sample SNN v4 (unchanged from R7, ~135 µs).
// ---------------------------------------------------------------------------
__global__ __launch_bounds__(256) void k_snn(const double* __restrict__ m1_0,
                                             const float* __restrict__ b1,
                                             const float* __restrict__ W1T,
                                             const float* __restrict__ W2T,
                                             const float* __restrict__ b2,
                                             const float* __restrict__ Wo,
                                             const float* __restrict__ bo,
                                             const int* __restrict__ nsteps_p,
                                             float* __restrict__ out) {
    __shared__ __align__(16) double pjbuf[H2_];      // 8 KB; aliased as l1idx
    __shared__ __align__(16) int l2idx[H2_];         // 4 KB
    __shared__ unsigned long long s1by[32];          // 256 B
    __shared__ unsigned long long s2nb[32];          // 256 B
    __shared__ int ncnt[2];
    __shared__ int anyb1[4], anyb2[4];

    int* l1idx = (int*)pjbuf;

    int b = blockIdx.x;
    int tid = threadIdx.x;
    int lane = tid & 63;
    int wv = tid >> 6;
    int T = nsteps_p[0];

    double m1r[8], m2r[4];
    float b1f[8], b2f[4];
    int cnt[4];

    const double* m1p = m1_0 + (size_t)b * H1_ + 8 * tid;
    {
        double2 v0 = *(const double2*)(m1p + 0);
        double2 v1 = *(const double2*)(m1p + 2);
        double2 v2 = *(const double2*)(m1p + 4);
        double2 v3 = *(const double2*)(m1p + 6);
        m1r[0] = v0.x; m1r[1] = v0.y; m1r[2] = v1.x; m1r[3] = v1.y;
        m1r[4] = v2.x; m1r[5] = v2.y; m1r[6] = v3.x; m1r[7] = v3.y;
    }
    {
        float4 f0 = *(const float4*)(b1 + 8 * tid);
        float4 f1 = *(const float4*)(b1 + 8 * tid + 4);
        b1f[0] = f0.x; b1f[1] = f0.y; b1f[2] = f0.z; b1f[3] = f0.w;
        b1f[4] = f1.x; b1f[5] = f1.y; b1f[6] = f1.z; b1f[7] = f1.w;
        float4 f2 = *(const float4*)(b2 + 4 * tid);
        b2f[0] = f2.x; b2f[1] = f2.y; b2f[2] = f2.z; b2f[3] = f2.w;
    }
#pragma unroll
    for (int q = 0; q < 4; ++q) { m2r[q] = 0.0; cnt[q] = 0; }

    int anyS2 = 0;

#define ACC2(v) { m2r[0] += (double)(v).x; m2r[1] += (double)(v).y; \
                  m2r[2] += (double)(v).z; m2r[3] += (double)(v).w; }

    for (int t = 0; t < T; ++t) {
        if (t > 0) {
#pragma unroll
            for (int q = 0; q < 8; ++q)
                m1r[q] = 0.9 * m1r[q] - (m1r[q] > 1.0 ? 1.0 : 0.0) + (double)b1f[q];
            if (anyS2) {
                int n2 = ncnt[1];
                const char* Wc = (const char*)W1T;
                size_t toff = (size_t)tid << 5;
                for (int k2 = 0; k2 < n2; ++k2) {
                    const float4* c4 = (const float4*)(Wc + l2idx[k2] + toff);
                    float4 va = c4[0];
                    float4 vb = c4[1];
                    m1r[0] += (double)va.x; m1r[1] += (double)va.y;
                    m1r[2] += (double)va.z; m1r[3] += (double)va.w;
                    m1r[4] += (double)vb.x; m1r[5] += (double)vb.y;
                    m1r[6] += (double)vb.z; m1r[7] += (double)vb.w;
                }
            }
        }
        unsigned bflag = 0;
#pragma unroll
        for (int q = 0; q < 8; ++q) bflag |= (m1r[q] > 1.0 ? 1u : 0u) << q;
        ((unsigned char*)s1by)[tid] = (unsigned char)bflag;
        {
            int wa = __any((int)bflag);
            if (lane == 0) anyb1[wv] = wa;
        }
#pragma unroll
        for (int q = 0; q < 4; ++q)
            m2r[q] = 0.9 * m2r[q] - (m2r[q] > 1.0 ? 1.0 : 0.0) + (double)b2f[q];
        {
            unsigned nib = 0;
#pragma unroll
            for (int q = 0; q < 4; ++q) nib |= (m2r[q] > 1.0 ? 1u : 0u) << q;
            ((unsigned char*)s2nb)[tid] = (unsigned char)nib;
            int wa = __any((int)nib);
            if (lane == 0) anyb2[wv] = wa;
        }
        __syncthreads();                                   // A
        int any1 = anyb1[0] | anyb1[1] | anyb1[2] | anyb1[3];
        if (any1) {
            if (tid < 64) {
                unsigned long long bits = (tid < 32) ? s1by[tid] : 0ULL;
                int pc = __popcll(bits);
                int sc = pc;
#pragma unroll
                for (int d = 1; d < 64; d <<= 1) {
                    int o = __shfl_up(sc, d);
                    if (tid >= d) sc += o;
                }
                if (tid == 63) ncnt[0] = sc;
                int off = sc - pc;
                int base = tid << 6;
                while (bits) {
                    l1idx[off++] = (base + __builtin_ctzll(bits)) << 12;
                    bits &= bits - 1;
                }
            }
            __syncthreads();                               // B
            {
                int n1 = ncnt[0];
                const char* Wc = (const char*)W2T;
                size_t toff = (size_t)tid << 4;
                int k = 0;
                for (; k + 8 <= n1; k += 8) {
                    int4 oa = *(const int4*)&l1idx[k];
                    int4 ob = *(const int4*)&l1idx[k + 4];
                    float4 v0 = *(const float4*)(Wc + oa.x + toff);
                    float4 v1 = *(const float4*)(Wc + oa.y + toff);
                    float4 v2 = *(const float4*)(Wc + oa.z + toff);
                    float4 v3 = *(const float4*)(Wc + oa.w + toff);
                    float4 v4 = *(const float4*)(Wc + ob.x + toff);
                    float4 v5 = *(const float4*)(Wc + ob.y + toff);
                    float4 v6 = *(const float4*)(Wc + ob.z + toff);
                    float4 v7 = *(const float4*)(Wc + ob.w + toff);
                    ACC2(v0); ACC2(v1); ACC2(v2); ACC2(v3);
                    ACC2(v4); ACC2(v5); ACC2(v6); ACC2(v7);
                }
                for (; k < n1; ++k) {
                    float4 v = *(const float4*)(Wc + l1idx[k] + toff);
                    ACC2(v);
                }
            }
            {
                unsigned nib = 0;
#pragma unroll
                for (int q = 0; q < 4; ++q) nib |= (m2r[q] > 1.0 ? 1u : 0u) << q;
                ((unsigned char*)s2nb)[tid] = (unsigned char)nib;
                int wa = __any((int)nib);
                if (lane == 0) anyb2[wv] = wa;
            }
            __syncthreads();                               // C
        }
        anyS2 = anyb2[0] | anyb2[1] | anyb2[2] | anyb2[3];
#pragma unroll
        for (int q = 0; q < 4; ++q) cnt[q] += (m2r[q] > 1.0) ? 1 : 0;
        if (anyS2) {
            if (tid < 64) {
                unsigned long long wbits = 0ULL;
                if (tid < 16) {
                    unsigned long long w0 = s2nb[2 * tid];
                    unsigned long long w1 = s2nb[2 * tid + 1];
                    w0 &= 0x0F0F0F0F0F0F0F0FULL;
                    w0 = (w0 | (w0 >> 4)) & 0x00FF00FF00FF00FFULL;
                    w0 = (w0 | (w0 >> 8)) & 0x0000FFFF0000FFFFULL;
                    w0 = (w0 | (w0 >> 16)) & 0x00000000FFFFFFFFULL;
                    w1 &= 0x0F0F0F0F0F0F0F0FULL;
                    w1 = (w1 | (w1 >> 4)) & 0x00FF00FF00FF00FFULL;
                    w1 = (w1 | (w1 >> 8)) & 0x0000FFFF0000FFFFULL;
                    w1 = (w1 | (w1 >> 16)) & 0x00000000FFFFFFFFULL;
                    wbits = w0 | (w1 << 32);
                }
                int pc = __popcll(wbits);
                int sc = pc;
#pragma unroll
                for (int d = 1; d < 64; d <<= 1) {
                    int o = __shfl_up(sc, d);
                    if (tid >= d) sc += o;
                }
                if (tid == 63) ncnt[1] = sc;
                int off = sc - pc;
                int base = tid << 6;
                while (wbits) {
                    l2idx[off++] = (base + __builtin_ctzll(wbits)) << 13;
                    wbits &= wbits - 1;
                }
            }
            __syncthreads();                               // D
        }
    }
#undef ACC2

    // ---- sparse epilogue ----
    __syncthreads();
#pragma unroll
    for (int q = 0; q < 4; ++q)
        pjbuf[4 * tid + q] = (double)cnt[q] / (double)T;
    {
        unsigned nib = 0;
#pragma unroll
        for (int q = 0; q < 4; ++q) nib |= (cnt[q] > 0 ? 1u : 0u) << q;
        ((unsigned char*)s2nb)[tid] = (unsigned char)nib;
    }
    __syncthreads();
    if (tid < 64) {
        unsigned long long wbits = 0ULL;
        if (tid < 16) {
            unsigned long long w0 = s2nb[2 * tid];
            unsigned long long w1 = s2nb[2 * tid + 1];
            w0 &= 0x0F0F0F0F0F0F0F0FULL;
            w0 = (w0 | (w0 >> 4)) & 0x00FF00FF00FF00FFULL;
            w0 = (w0 | (w0 >> 8)) & 0x0000FFFF0000FFFFULL;
            w0 = (w0 | (w0 >> 16)) & 0x00000000FFFFFFFFULL;
            w1 &= 0x0F0F0F0F0F0F0F0FULL;
            w1 = (w1 | (w1 >> 4)) & 0x00FF00FF00FF00FFULL;
            w1 = (w1 | (w1 >> 8)) & 0x0000FFFF0000FFFFULL;
            w1 = (w1 | (w1 >> 16)) & 0x00000000FFFFFFFFULL;
            wbits = w0 | (w1 << 32);
        }
        int pc = __popcll(wbits);
        int sc = pc;
#pragma unroll
        for (int d = 1; d < 64; d <<= 1) {
            int o = __shfl_up(sc, d);
            if (tid >= d) sc += o;
        }
        if (tid == 63) ncnt[1] = sc;
        int off = sc - pc;
        int base = tid << 6;
        while (wbits) {
            l2idx[off++] = base + __builtin_ctzll(wbits);
            wbits &= wbits - 1;
        }
    }
    __syncthreads();
    if (tid < C_) {
        int c = tid;
        int na = ncnt[1];
        const float* worow = &Wo[(size_t)c * H2_];
        double acc = 0.0;
        for (int k = 0; k < na; ++k) {
            int j = l2idx[k];
            acc += pjbuf[j] * (double)worow[j];
        }
        out[(size_t)b * C_ + c] = (float)(acc + (double)bo[c]);
    }
}

// ---------------------------------------------------------------------------
extern "C" void kernel_launch(void* const* d_in, const int* in_sizes, int n_in,
                              void* d_out, int out_size, void* d_ws, size_t ws_size,
                              hipStream_t stream) {
    const float* x  = (const float*)d_in[0];   // [4096,1024]
    const float* W1 = (const float*)d_in[1];   // [2048,1024]
    const float* b1 = (const float*)d_in[2];   // [2048]
    const float* W2 = (const float*)d_in[3];   // [1024,2048]
    const float* b2 = (const float*)d_in[4];   // [1024]
    const float* Wo = (const float*)d_in[5];   // [64,1024]
    const float* bo = (const float*)d_in[6];   // [64]
    const int* nst  = (const int*)d_in[7];     // [1] = 20
    float* out = (float*)d_out;

    size_t off_m1   = 0;                                   // f64 [4096][2048]
    size_t off_w1t  = off_m1 + (size_t)B_ * H1_ * 8;
    size_t off_w2t  = off_w1t + (size_t)D_ * H1_ * 4;
    size_t off_flag = off_w2t + (size_t)H1_ * H2_ * 4;
    size_t need     = off_flag + 64;
    if (ws_size < need) return;

    double* m1ws = (double*)((char*)d_ws + off_m1);
    float*  W1T  = (float*)((char*)d_ws + off_w1t);
    float*  W2T  = (float*)((char*)d_ws + off_w2t);
    int*    flag = (int*)((char*)d_ws + off_flag);

    k_probe<<<1, 64, 0, stream>>>(flag);

    k_transpose<<<dim3(D_ / 32, H1_ / 32), dim3(32, 8), 0, stream>>>(W1, W1T, H1_, D_);
    k_transpose<<<dim3(H1_ / 32, H2_ / 32), dim3(32, 8), 0, stream>>>(W2, W2T, H2_, H1_);

    k_gemm_mfma<<<dim3(B_ / GBM, H1_ / GBN), 512, 0, stream>>>(x, W1, b1, m1ws, flag);
    k_gemm1<<<dim3(B_ / BM, H1_ / BN), 256, 0, stream>>>(x, W1, b1, m1ws, flag);

    k_snn<<<B_, 256, 0, stream>>>(m1ws, b1, W1T, W2T, b2, Wo, bo, nst, out);
}

// Round 12
// 441.939 us; speedup vs baseline: 1.0208x; 1.0208x over previous
//
#include <hip/hip_runtime.h>
#include <hip/hip_bf16.h>

// Sizes (fixed by the reference): B=4096, D=1024, H1=2048, H2=1024, C=64, T=20
#define B_   4096
#define D_   1024
#define H1_  2048
#define H2_  1024
#define C_   64

typedef double d4 __attribute__((ext_vector_type(4)));

#if defined(__has_builtin)
#  if __has_builtin(__builtin_amdgcn_mfma_f64_16x16x4f64)
#    define MFMA64(A, B, C) __builtin_amdgcn_mfma_f64_16x16x4f64((A), (B), (C), 0, 0, 0)
#    define HAVE_MFMA64 1
#  elif __has_builtin(__builtin_amdgcn_mfma_f64_16x16x4_f64)
#    define MFMA64(A, B, C) __builtin_amdgcn_mfma_f64_16x16x4_f64((A), (B), (C), 0, 0, 0)
#    define HAVE_MFMA64 1
#  endif
#endif

// ---------------------------------------------------------------------------
// Probe: discover v_mfma_f64_16x16x4 D-fragment layout at runtime.
// ---------------------------------------------------------------------------
__global__ void k_probe(int* flag) {
#if defined(HAVE_MFMA64)
    int lane = threadIdx.x & 63;
    int lr = lane & 15, lk = lane >> 4;
    double a  = (double)(5 * lr + 3 * lk + 1);    // A[r][k] = 5r+3k+1
    double bb = (double)(11 * lk + 2 * lr + 2);   // B[k][c] = 11k+2c+2
    d4 c = {0.0, 0.0, 0.0, 0.0};
    c = MFMA64(a, bb, c);
    int okm[4] = {1, 1, 1, 1};
#pragma unroll
    for (int j = 0; j < 4; ++j) {
        double e1 = 0, e2 = 0, e3 = 0, e4 = 0;
        for (int k = 0; k < 4; ++k) {
            e1 += (double)(5 * (4 * lk + j) + 3 * k + 1) * (double)(11 * k + 2 * lr + 2);
            e2 += (double)(5 * lr + 3 * k + 1) * (double)(11 * k + 2 * (4 * lk + j) + 2);
            e3 += (double)(5 * (lk + 4 * j) + 3 * k + 1) * (double)(11 * k + 2 * lr + 2);
            e4 += (double)(5 * lr + 3 * k + 1) * (double)(11 * k + 2 * (lk + 4 * j) + 2);
        }
        if (c[j] != e1) okm[0] = 0;
        if (c[j] != e2) okm[1] = 0;
        if (c[j] != e3) okm[2] = 0;
        if (c[j] != e4) okm[3] = 0;
    }
    int f = 0;
    for (int m = 3; m >= 0; --m) {
        unsigned long long all = __ballot(okm[m] != 0);
        if (all == ~0ULL) f = m + 1;
    }
    if (lane == 0) flag[0] = f;
#else
    if ((threadIdx.x & 63) == 0) flag[0] = 0;
#endif
}

// ---------------------------------------------------------------------------
// Transpose: out[c][r] = in[r][c]   (f32, 32x32 LDS tiles)
// ---------------------------------------------------------------------------
__global__ __launch_bounds__(256) void k_transpose(const float* __restrict__ in,
                                                   float* __restrict__ out,
                                                   int R, int C) {
    __shared__ float t[32][33];
    int c0 = blockIdx.x * 32;
    int r0 = blockIdx.y * 32;
    int lx = threadIdx.x;
    int ly = threadIdx.y;
#pragma unroll
    for (int q = 0; q < 4; ++q) {
        int rr = ly + 8 * q;
        t[rr][lx] = in[(size_t)(r0 + rr) * C + (c0 + lx)];
    }
    __syncthreads();
#pragma unroll
    for (int q = 0; q < 4; ++q) {
        int cc = ly + 8 * q;
        out[(size_t)(c0 + cc) * R + (r0 + lx)] = t[lx][cc];
    }
}

// ---------------------------------------------------------------------------
// f64 MFMA GEMM v7: tile 128x64, GBK=32, 512 thr (8 waves, wave-tile 32x32).
//  - v5's per-tile MFMA depth (32 MFMA/tile/wave, 32 k-tiles)
//  - v6's grid: 32x32 = 1024 blocks = 4 blocks/CU -> 8 waves/SIMD from 4
//    independent blocks; barrier drains idle only 2/8 waves.
//  - f32 LDS (convert at fragment read; (double)(float) exact): 27 KB/block.
//  - conflict-free pads: AIDX32(k,r)=136k+8(k>>2)+8(k&1)+r (A),
//    BIDX32(k,r)=72k+8(k>>2)+8(k&1)+r (B): writes tile all 32 banks; read
//    lk-pairs land +16 mod 32 -> disjoint halves. Zero conflicts.
// k-order per output element identical to v5/v6 -> bit-identical, absmax 0.
// ---------------------------------------------------------------------------
#define GBM 128
#define GBN 64
#define GBK 32
#define ASZ32 4416   // AIDX32(31,127)+1 = 4407, rounded up
#define BSZ32 2368   // BIDX32(31,63)+1  = 2359, rounded up
__device__ __forceinline__ int AIDX32(int k, int r) {
    return k * 136 + ((k >> 2) << 3) + ((k & 1) << 3) + r;
}
__device__ __forceinline__ int BIDX32(int k, int r) {
    return k * 72 + ((k >> 2) << 3) + ((k & 1) << 3) + r;
}
__global__ __launch_bounds__(512, 8) void k_gemm_mfma(const float* __restrict__ x,
                                                      const float* __restrict__ W1,
                                                      const float* __restrict__ b1,
                                                      double* __restrict__ m1out,
                                                      const int* __restrict__ flag) {
#if defined(HAVE_MFMA64)
    int fm = flag[0];
    if (fm < 1 || fm > 4) return;
    __shared__ float As[ASZ32];   // 17.7 KB
    __shared__ float Bs[BSZ32];   //  9.5 KB  (27.2 KB -> 4 blocks/CU)

    int tid = threadIdx.x;
    int m0 = blockIdx.x * GBM;
    int n0 = blockIdx.y * GBN;
    int w = tid >> 6, lane = tid & 63;
    int wr = w >> 1;        // 0..3 : 32-row band
    int wc = w & 1;         // 0..1 : 32-col band
    int lr = lane & 15, lk = lane >> 4;

    // A staging: row srowA (0..127), k groups 4gA.. and 16+4gA.. (2 float4)
    int srowA = tid >> 2;
    int gA    = tid & 3;
    int woffA = AIDX32(4 * gA, srowA);
    // B staging: row srowB (0..63), k group 4gB (1 float4); 8 lanes/row ->
    // 128B contiguous global reads.
    int srowB = tid >> 3;
    int gB    = tid & 7;
    int woffB = BIDX32(4 * gB, srowB);

    const float* xrow = x  + (size_t)(m0 + srowA) * D_;
    const float* wrow = W1 + (size_t)(n0 + srowB) * D_;

    d4 acc[2][2];
#pragma unroll
    for (int i = 0; i < 2; ++i)
#pragma unroll
        for (int j = 0; j < 2; ++j) acc[i][j] = (d4){0.0, 0.0, 0.0, 0.0};

    for (int k0 = 0; k0 < D_; k0 += GBK) {
        float4 a0 = *(const float4*)&xrow[k0 + 4 * gA];
        float4 a1 = *(const float4*)&xrow[k0 + 4 * gA + 16];
        float4 bv = *(const float4*)&wrow[k0 + 4 * gB];
        __syncthreads();   // all fragment reads of previous tile complete
        // A rows 4gA+q: in-group q offsets {0,144,272,416}; +16 k adds 2208
        As[woffA +    0] = a0.x;
        As[woffA +  144] = a0.y;
        As[woffA +  272] = a0.z;
        As[woffA +  416] = a0.w;
        As[woffA + 2208] = a1.x;
        As[woffA + 2352] = a1.y;
        As[woffA + 2480] = a1.z;
        As[woffA + 2624] = a1.w;
        // B rows 4gB+q: in-group q offsets {0,80,144,224}
        Bs[woffB +   0] = bv.x;
        Bs[woffB +  80] = bv.y;
        Bs[woffB + 144] = bv.z;
        Bs[woffB + 224] = bv.w;
        __syncthreads();   // tile staged
#pragma unroll
        for (int kb = 0; kb < 8; ++kb) {
            int k = kb * 4 + lk;
            int abase = AIDX32(k, wr * 32 + lr);
            int bbase = BIDX32(k, wc * 32 + lr);
            double a[2], bfr[2];
#pragma unroll
            for (int i = 0; i < 2; ++i) a[i]   = (double)As[abase + 16 * i];
#pragma unroll
            for (int j = 0; j < 2; ++j) bfr[j] = (double)Bs[bbase + 16 * j];
#pragma unroll
            for (int i = 0; i < 2; ++i)
#pragma unroll
                for (int j = 0; j < 2; ++j)
                    acc[i][j] = MFMA64(a[i], bfr[j], acc[i][j]);
        }
    }

    // epilogue: D-mapping selected by fm
#pragma unroll
    for (int j = 0; j < 2; ++j)
#pragma unroll
        for (int i = 0; i < 2; ++i)
#pragma unroll
            for (int r = 0; r < 4; ++r) {
                int rin = (fm == 1) ? (4 * lk + r) : (fm == 2) ? lr
                        : (fm == 3) ? (lk + 4 * r) : lr;
                int cin = (fm == 1) ? lr : (fm == 2) ? (4 * lk + r)
                        : (fm == 3) ? lr : (lk + 4 * r);
                int row = m0 + wr * 32 + 16 * i + rin;
                int col = n0 + wc * 32 + 16 * j + cin;
                m1out[(size_t)row * H1_ + col] = acc[i][j][r] + (double)b1[col];
            }
#else
    (void)x; (void)W1; (void)b1; (void)m1out; (void)flag;
#endif
}

// ---------------------------------------------------------------------------
// Fallback VALU f64 GEMM (proven). Runs iff flag not in {1..4}.
// ---------------------------------------------------------------------------
#define BM 128
#define BN 128
#define BK 8
__global__ __launch_bounds__(256) void k_gemm1(const float* __restrict__ x,
                                               const float* __restrict__ W1,
                                               const float* __restrict__ b1,
                                               double* __restrict__ m1out,
                                               const int* __restrict__ flag) {
    int fm = flag[0];
    if (fm >= 1 && fm <= 4) return;
    __shared__ double As[BK][BM + 4];
    __shared__ double Bs[BK][BN + 4];

    int tid = threadIdx.x;
    int m0 = blockIdx.x * BM;
    int n0 = blockIdx.y * BN;
    int tx = tid & 15;
    int ty = tid >> 4;
    int lr = tid >> 1;
    int lk = (tid & 1) * 4;

    double acc[8][8] = {};

    for (int k0 = 0; k0 < D_; k0 += BK) {
        float4 av = *(const float4*)&x [(size_t)(m0 + lr) * D_ + k0 + lk];
        float4 bv = *(const float4*)&W1[(size_t)(n0 + lr) * D_ + k0 + lk];
        __syncthreads();
        As[lk + 0][lr] = (double)av.x;
        As[lk + 1][lr] = (double)av.y;
        As[lk + 2][lr] = (double)av.z;
        As[lk + 3][lr] = (double)av.w;
        Bs[lk + 0][lr] = (double)bv.x;
        Bs[lk + 1][lr] = (double)bv.y;
        Bs[lk + 2][lr] = (double)bv.z;
        Bs[lk + 3][lr] = (double)bv.w;
        __syncthreads();
#pragma unroll
        for (int kk = 0; kk < BK; ++kk) {
            double a[8], b[8];
#pragma unroll
            for (int i = 0; i < 8; ++i) a[i] = As[kk][tx + 16 * i];
#pragma unroll
            for (int j = 0; j < 8; ++j) b[j] = Bs[kk][ty + 16 * j];
#pragma unroll
            for (int i = 0; i < 8; ++i)
#pragma unroll
                for (int j = 0; j < 8; ++j)
                    acc[i][j] += a[i] * b[j];
        }
    }
#pragma unroll
    for (int j = 0; j < 8; ++j) {
        double bj = (double)b1[n0 + ty + 16 * j];
#pragma unroll
        for (int i = 0; i < 8; ++i) {
            m1out[(size_t)(m0 + tx + 16 * i) * H1_ + (n0 + ty + 16 * j)] =
                acc[i][j] + bj;
        }
    }
}

// ---------------------------------------------------------------------------
// Persistent per-sample SNN v4 (unchanged from R7, ~135 µs).
// ---------------------------------------------------------------------------
__global__ __launch_bounds__(256) void k_snn(const double* __restrict__ m1_0,
                                             const float* __restrict__ b1,
                                             const float* __restrict__ W1T,
                                             const float* __restrict__ W2T,
                                             const float* __restrict__ b2,
                                             const float* __restrict__ Wo,
                                             const float* __restrict__ bo,
                                             const int* __restrict__ nsteps_p,
                                             float* __restrict__ out) {
    __shared__ __align__(16) double pjbuf[H2_];      // 8 KB; aliased as l1idx
    __shared__ __align__(16) int l2idx[H2_];         // 4 KB
    __shared__ unsigned long long s1by[32];          // 256 B
    __shared__ unsigned long long s2nb[32];          // 256 B
    __shared__ int ncnt[2];
    __shared__ int anyb1[4], anyb2[4];

    int* l1idx = (int*)pjbuf;

    int b = blockIdx.x;
    int tid = threadIdx.x;
    int lane = tid & 63;
    int wv = tid >> 6;
    int T = nsteps_p[0];

    double m1r[8], m2r[4];
    float b1f[8], b2f[4];
    int cnt[4];

    const double* m1p = m1_0 + (size_t)b * H1_ + 8 * tid;
    {
        double2 v0 = *(const double2*)(m1p + 0);
        double2 v1 = *(const double2*)(m1p + 2);
        double2 v2 = *(const double2*)(m1p + 4);
        double2 v3 = *(const double2*)(m1p + 6);
        m1r[0] = v0.x; m1r[1] = v0.y; m1r[2] = v1.x; m1r[3] = v1.y;
        m1r[4] = v2.x; m1r[5] = v2.y; m1r[6] = v3.x; m1r[7] = v3.y;
    }
    {
        float4 f0 = *(const float4*)(b1 + 8 * tid);
        float4 f1 = *(const float4*)(b1 + 8 * tid + 4);
        b1f[0] = f0.x; b1f[1] = f0.y; b1f[2] = f0.z; b1f[3] = f0.w;
        b1f[4] = f1.x; b1f[5] = f1.y; b1f[6] = f1.z; b1f[7] = f1.w;
        float4 f2 = *(const float4*)(b2 + 4 * tid);
        b2f[0] = f2.x; b2f[1] = f2.y; b2f[2] = f2.z; b2f[3] = f2.w;
    }
#pragma unroll
    for (int q = 0; q < 4; ++q) { m2r[q] = 0.0; cnt[q] = 0; }

    int anyS2 = 0;

#define ACC2(v) { m2r[0] += (double)(v).x; m2r[1] += (double)(v).y; \
                  m2r[2] += (double)(v).z; m2r[3] += (double)(v).w; }

    for (int t = 0; t < T; ++t) {
        if (t > 0) {
#pragma unroll
            for (int q = 0; q < 8; ++q)
                m1r[q] = 0.9 * m1r[q] - (m1r[q] > 1.0 ? 1.0 : 0.0) + (double)b1f[q];
            if (anyS2) {
                int n2 = ncnt[1];
                const char* Wc = (const char*)W1T;
                size_t toff = (size_t)tid << 5;
                for (int k2 = 0; k2 < n2; ++k2) {
                    const float4* c4 = (const float4*)(Wc + l2idx[k2] + toff);
                    float4 va = c4[0];
                    float4 vb = c4[1];
                    m1r[0] += (double)va.x; m1r[1] += (double)va.y;
                    m1r[2] += (double)va.z; m1r[3] += (double)va.w;
                    m1r[4] += (double)vb.x; m1r[5] += (double)vb.y;
                    m1r[6] += (double)vb.z; m1r[7] += (double)vb.w;
                }
            }
        }
        unsigned bflag = 0;
#pragma unroll
        for (int q = 0; q < 8; ++q) bflag |= (m1r[q] > 1.0 ? 1u : 0u) << q;
        ((unsigned char*)s1by)[tid] = (unsigned char)bflag;
        {
            int wa = __any((int)bflag);
            if (lane == 0) anyb1[wv] = wa;
        }
#pragma unroll
        for (int q = 0; q < 4; ++q)
            m2r[q] = 0.9 * m2r[q] - (m2r[q] > 1.0 ? 1.0 : 0.0) + (double)b2f[q];
        {
            unsigned nib = 0;
#pragma unroll
            for (int q = 0; q < 4; ++q) nib |= (m2r[q] > 1.0 ? 1u : 0u) << q;
            ((unsigned char*)s2nb)[tid] = (unsigned char)nib;
            int wa = __any((int)nib);
            if (lane == 0) anyb2[wv] = wa;
        }
        __syncthreads();                                   // A
        int any1 = anyb1[0] | anyb1[1] | anyb1[2] | anyb1[3];
        if (any1) {
            if (tid < 64) {
                unsigned long long bits = (tid < 32) ? s1by[tid] : 0ULL;
                int pc = __popcll(bits);
                int sc = pc;
#pragma unroll
                for (int d = 1; d < 64; d <<= 1) {
                    int o = __shfl_up(sc, d);
                    if (tid >= d) sc += o;
                }
                if (tid == 63) ncnt[0] = sc;
                int off = sc - pc;
                int base = tid << 6;
                while (bits) {
                    l1idx[off++] = (base + __builtin_ctzll(bits)) << 12;
                    bits &= bits - 1;
                }
            }
            __syncthreads();                               // B
            {
                int n1 = ncnt[0];
                const char* Wc = (const char*)W2T;
                size_t toff = (size_t)tid << 4;
                int k = 0;
                for (; k + 8 <= n1; k += 8) {
                    int4 oa = *(const int4*)&l1idx[k];
                    int4 ob = *(const int4*)&l1idx[k + 4];
                    float4 v0 = *(const float4*)(Wc + oa.x + toff);
                    float4 v1 = *(const float4*)(Wc + oa.y + toff);
                    float4 v2 = *(const float4*)(Wc + oa.z + toff);
                    float4 v3 = *(const float4*)(Wc + oa.w + toff);
                    float4 v4 = *(const float4*)(Wc + ob.x + toff);
                    float4 v5 = *(const float4*)(Wc + ob.y + toff);
                    float4 v6 = *(const float4*)(Wc + ob.z + toff);
                    float4 v7 = *(const float4*)(Wc + ob.w + toff);
                    ACC2(v0); ACC2(v1); ACC2(v2); ACC2(v3);
                    ACC2(v4); ACC2(v5); ACC2(v6); ACC2(v7);
                }
                for (; k < n1; ++k) {
                    float4 v = *(const float4*)(Wc + l1idx[k] + toff);
                    ACC2(v);
                }
            }
            {
                unsigned nib = 0;
#pragma unroll
                for (int q = 0; q < 4; ++q) nib |= (m2r[q] > 1.0 ? 1u : 0u) << q;
                ((unsigned char*)s2nb)[tid] = (unsigned char)nib;
                int wa = __any((int)nib);
                if (lane == 0) anyb2[wv] = wa;
            }
            __syncthreads();                               // C
        }
        anyS2 = anyb2[0] | anyb2[1] | anyb2[2] | anyb2[3];
#pragma unroll
        for (int q = 0; q < 4; ++q) cnt[q] += (m2r[q] > 1.0) ? 1 : 0;
        if (anyS2) {
            if (tid < 64) {
                unsigned long long wbits = 0ULL;
                if (tid < 16) {
                    unsigned long long w0 = s2nb[2 * tid];
                    unsigned long long w1 = s2nb[2 * tid + 1];
                    w0 &= 0x0F0F0F0F0F0F0F0FULL;
                    w0 = (w0 | (w0 >> 4)) & 0x00FF00FF00FF00FFULL;
                    w0 = (w0 | (w0 >> 8)) & 0x0000FFFF0000FFFFULL;
                    w0 = (w0 | (w0 >> 16)) & 0x00000000FFFFFFFFULL;
                    w1 &= 0x0F0F0F0F0F0F0F0FULL;
                    w1 = (w1 | (w1 >> 4)) & 0x00FF00FF00FF00FFULL;
                    w1 = (w1 | (w1 >> 8)) & 0x0000FFFF0000FFFFULL;
                    w1 = (w1 | (w1 >> 16)) & 0x00000000FFFFFFFFULL;
                    wbits = w0 | (w1 << 32);
                }
                int pc = __popcll(wbits);
                int sc = pc;
#pragma unroll
                for (int d = 1; d < 64; d <<= 1) {
                    int o = __shfl_up(sc, d);
                    if (tid >= d) sc += o;
                }
                if (tid == 63) ncnt[1] = sc;
                int off = sc - pc;
                int base = tid << 6;
                while (wbits) {
                    l2idx[off++] = (base + __builtin_ctzll(wbits)) << 13;
                    wbits &= wbits - 1;
                }
            }
            __syncthreads();                               // D
        }
    }
#undef ACC2

    // ---- sparse epilogue ----
    __syncthreads();
#pragma unroll
    for (int q = 0; q < 4; ++q)
        pjbuf[4 * tid + q] = (double)cnt[q] / (double)T;
    {
        unsigned nib = 0;
#pragma unroll
        for (int q = 0; q < 4; ++q) nib |= (cnt[q] > 0 ? 1u : 0u) << q;
        ((unsigned char*)s2nb)[tid] = (unsigned char)nib;
    }
    __syncthreads();
    if (tid < 64) {
        unsigned long long wbits = 0ULL;
        if (tid < 16) {
            unsigned long long w0 = s2nb[2 * tid];
            unsigned long long w1 = s2nb[2 * tid + 1];
            w0 &= 0x0F0F0F0F0F0F0F0FULL;
            w0 = (w0 | (w0 >> 4)) & 0x00FF00FF00FF00FFULL;
            w0 = (w0 | (w0 >> 8)) & 0x0000FFFF0000FFFFULL;
            w0 = (w0 | (w0 >> 16)) & 0x00000000FFFFFFFFULL;
            w1 &= 0x0F0F0F0F0F0F0F0FULL;
            w1 = (w1 | (w1 >> 4)) & 0x00FF00FF00FF00FFULL;
            w1 = (w1 | (w1 >> 8)) & 0x0000FFFF0000FFFFULL;
            w1 = (w1 | (w1 >> 16)) & 0x00000000FFFFFFFFULL;
            wbits = w0 | (w1 << 32);
        }
        int pc = __popcll(wbits);
        int sc = pc;
#pragma unroll
        for (int d = 1; d < 64; d <<= 1) {
            int o = __shfl_up(sc, d);
            if (tid >= d) sc += o;
        }
        if (tid == 63) ncnt[1] = sc;
        int off = sc - pc;
        int base = tid << 6;
        while (wbits) {
            l2idx[off++] = base + __builtin_ctzll(wbits);
            wbits &= wbits - 1;
        }
    }
    __syncthreads();
    if (tid < C_) {
        int c = tid;
        int na = ncnt[1];
        const float* worow = &Wo[(size_t)c * H2_];
        double acc = 0.0;
        for (int k = 0; k < na; ++k) {
            int j = l2idx[k];
            acc += pjbuf[j] * (double)worow[j];
        }
        out[(size_t)b * C_ + c] = (float)(acc + (double)bo[c]);
    }
}

// ---------------------------------------------------------------------------
extern "C" void kernel_launch(void* const* d_in, const int* in_sizes, int n_in,
                              void* d_out, int out_size, void* d_ws, size_t ws_size,
                              hipStream_t stream) {
    const float* x  = (const float*)d_in[0];   // [4096,1024]
    const float* W1 = (const float*)d_in[1];   // [2048,1024]
    const float* b1 = (const float*)d_in[2];   // [2048]
    const float* W2 = (const float*)d_in[3];   // [1024,2048]
    const float* b2 = (const float*)d_in[4];   // [1024]
    const float* Wo = (const float*)d_in[5];   // [64,1024]
    const float* bo = (const float*)d_in[6];   // [64]
    const int* nst  = (const int*)d_in[7];     // [1] = 20
    float* out = (float*)d_out;

    size_t off_m1   = 0;                                   // f64 [4096][2048]
    size_t off_w1t  = off_m1 + (size_t)B_ * H1_ * 8;
    size_t off_w2t  = off_w1t + (size_t)D_ * H1_ * 4;
    size_t off_flag = off_w2t + (size_t)H1_ * H2_ * 4;
    size_t need     = off_flag + 64;
    if (ws_size < need) return;

    double* m1ws = (double*)((char*)d_ws + off_m1);
    float*  W1T  = (float*)((char*)d_ws + off_w1t);
    float*  W2T  = (float*)((char*)d_ws + off_w2t);
    int*    flag = (int*)((char*)d_ws + off_flag);

    k_probe<<<1, 64, 0, stream>>>(flag);

    k_transpose<<<dim3(D_ / 32, H1_ / 32), dim3(32, 8), 0, stream>>>(W1, W1T, H1_, D_);
    k_transpose<<<dim3(H1_ / 32, H2_ / 32), dim3(32, 8), 0, stream>>>(W2, W2T, H2_, H1_);

    k_gemm_mfma<<<dim3(B_ / GBM, H1_ / GBN), 512, 0, stream>>>(x, W1, b1, m1ws, flag);
    k_gemm1<<<dim3(B_ / BM, H1_ / BN), 256, 0, stream>>>(x, W1, b1, m1ws, flag);

    k_snn<<<B_, 256, 0, stream>>>(m1ws, b1, W1T, W2T, b2, Wo, bo, nst, out);
}

// Round 13
// 440.906 us; speedup vs baseline: 1.0232x; 1.0023x over previous
//
#include <hip/hip_runtime.h>
#include <hip/hip_bf16.h>

// Sizes (fixed by the reference): B=4096, D=1024, H1=2048, H2=1024, C=64, T=20
#define B_   4096
#define D_   1024
#define H1_  2048
#define H2_  1024
#define C_   64

typedef double d4 __attribute__((ext_vector_type(4)));

#if defined(__has_builtin)
#  if __has_builtin(__builtin_amdgcn_mfma_f64_16x16x4f64)
#    define MFMA64(A, B, C) __builtin_amdgcn_mfma_f64_16x16x4f64((A), (B), (C), 0, 0, 0)
#    define HAVE_MFMA64 1
#  elif __has_builtin(__builtin_amdgcn_mfma_f64_16x16x4_f64)
#    define MFMA64(A, B, C) __builtin_amdgcn_mfma_f64_16x16x4_f64((A), (B), (C), 0, 0, 0)
#    define HAVE_MFMA64 1
#  endif
#endif

// ---------------------------------------------------------------------------
// Probe: discover v_mfma_f64_16x16x4 D-fragment layout at runtime.
// ---------------------------------------------------------------------------
__global__ void k_probe(int* flag) {
#if defined(HAVE_MFMA64)
    int lane = threadIdx.x & 63;
    int lr = lane & 15, lk = lane >> 4;
    double a  = (double)(5 * lr + 3 * lk + 1);    // A[r][k] = 5r+3k+1
    double bb = (double)(11 * lk + 2 * lr + 2);   // B[k][c] = 11k+2c+2
    d4 c = {0.0, 0.0, 0.0, 0.0};
    c = MFMA64(a, bb, c);
    int okm[4] = {1, 1, 1, 1};
#pragma unroll
    for (int j = 0; j < 4; ++j) {
        double e1 = 0, e2 = 0, e3 = 0, e4 = 0;
        for (int k = 0; k < 4; ++k) {
            e1 += (double)(5 * (4 * lk + j) + 3 * k + 1) * (double)(11 * k + 2 * lr + 2);
            e2 += (double)(5 * lr + 3 * k + 1) * (double)(11 * k + 2 * (4 * lk + j) + 2);
            e3 += (double)(5 * (lk + 4 * j) + 3 * k + 1) * (double)(11 * k + 2 * lr + 2);
            e4 += (double)(5 * lr + 3 * k + 1) * (double)(11 * k + 2 * (lk + 4 * j) + 2);
        }
        if (c[j] != e1) okm[0] = 0;
        if (c[j] != e2) okm[1] = 0;
        if (c[j] != e3) okm[2] = 0;
        if (c[j] != e4) okm[3] = 0;
    }
    int f = 0;
    for (int m = 3; m >= 0; --m) {
        unsigned long long all = __ballot(okm[m] != 0);
        if (all == ~0ULL) f = m + 1;
    }
    if (lane == 0) flag[0] = f;
#else
    if ((threadIdx.x & 63) == 0) flag[0] = 0;
#endif
}

// ---------------------------------------------------------------------------
// Transpose: out[c][r] = in[r][c]   (f32, 32x32 LDS tiles)
// ---------------------------------------------------------------------------
__global__ __launch_bounds__(256) void k_transpose(const float* __restrict__ in,
                                                   float* __restrict__ out,
                                                   int R, int C) {
    __shared__ float t[32][33];
    int c0 = blockIdx.x * 32;
    int r0 = blockIdx.y * 32;
    int lx = threadIdx.x;
    int ly = threadIdx.y;
#pragma unroll
    for (int q = 0; q < 4; ++q) {
        int rr = ly + 8 * q;
        t[rr][lx] = in[(size_t)(r0 + rr) * C + (c0 + lx)];
    }
    __syncthreads();
#pragma unroll
    for (int q = 0; q < 4; ++q) {
        int cc = ly + 8 * q;
        out[(size_t)(c0 + cc) * R + (r0 + lx)] = t[lx][cc];
    }
}

// ---------------------------------------------------------------------------
// f64 MFMA GEMM v8: tile 128x128, GBK=64, 512 thr, wave-tile 64x32 (= v5
// wave layout & epilogue). 16 k-tiles -> 32 barrier windows (half of v5).
// f32 LDS (convert at fragment read; (double)(float) exact): 2x34.5 KB ->
// 2 blocks/CU, 4 waves/SIMD (v5 occupancy). Conflict-free pad (v7-family):
// AIDX32(k,r) = 136k + 8*(k>>2) + 8*(k&1) + r; in-group offsets
// {0,144,272,416}, +16 k adds 2208. k-order per output element identical
// ascending 4-chunks -> bit-identical result, absmax 0.
// ---------------------------------------------------------------------------
#define GBM 128
#define GBN 128
#define GBK 64
#define ASZ32 8832   // AIDX32(63,127)+1 = 8824, rounded up
__device__ __forceinline__ int AIDX32(int k, int r) {
    return k * 136 + ((k >> 2) << 3) + ((k & 1) << 3) + r;
}
__global__ __launch_bounds__(512, 4) void k_gemm_mfma(const float* __restrict__ x,
                                                      const float* __restrict__ W1,
                                                      const float* __restrict__ b1,
                                                      double* __restrict__ m1out,
                                                      const int* __restrict__ flag) {
#if defined(HAVE_MFMA64)
    int fm = flag[0];
    if (fm < 1 || fm > 4) return;
    __shared__ float As[ASZ32];   // 34.5 KB
    __shared__ float Bs[ASZ32];   // 34.5 KB  (69 KB -> 2 blocks/CU)

    int tid = threadIdx.x;
    int m0 = blockIdx.x * GBM;
    int n0 = blockIdx.y * GBN;
    int w = tid >> 6, lane = tid & 63;
    int wr = w >> 2;        // 0..1 : 64-row half
    int wc = w & 3;         // 0..3 : 32-col quarter
    int lr = lane & 15, lk = lane >> 4;

    int srow = tid >> 2;           // 0..127
    int g    = tid & 3;            // k sub-group
    int woff = AIDX32(4 * g, srow);   // in-group offsets {0,144,272,416}; +16k: +2208

    const float* xrow = x  + (size_t)(m0 + srow) * D_;
    const float* wrow = W1 + (size_t)(n0 + srow) * D_;

    d4 acc[4][2];
#pragma unroll
    for (int i = 0; i < 4; ++i)
#pragma unroll
        for (int j = 0; j < 2; ++j) acc[i][j] = (d4){0.0, 0.0, 0.0, 0.0};

    for (int k0 = 0; k0 < D_; k0 += GBK) {
        float4 av[4], bv[4];
#pragma unroll
        for (int q = 0; q < 4; ++q) {
            av[q] = *(const float4*)&xrow[k0 + 4 * g + 16 * q];
            bv[q] = *(const float4*)&wrow[k0 + 4 * g + 16 * q];
        }
        __syncthreads();   // all fragment reads of previous tile complete
#pragma unroll
        for (int q = 0; q < 4; ++q) {
            int o = woff + q * 2208;
            As[o +   0] = av[q].x;
            As[o + 144] = av[q].y;
            As[o + 272] = av[q].z;
            As[o + 416] = av[q].w;
            Bs[o +   0] = bv[q].x;
            Bs[o + 144] = bv[q].y;
            Bs[o + 272] = bv[q].z;
            Bs[o + 416] = bv[q].w;
        }
        __syncthreads();   // tile staged
#pragma unroll
        for (int kb = 0; kb < 16; ++kb) {
            int k = kb * 4 + lk;
            int abase = AIDX32(k, wr * 64 + lr);
            int bbase = AIDX32(k, wc * 32 + lr);
            double a[4], bfr[2];
#pragma unroll
            for (int i = 0; i < 4; ++i) a[i]   = (double)As[abase + 16 * i];
#pragma unroll
            for (int j = 0; j < 2; ++j) bfr[j] = (double)Bs[bbase + 16 * j];
#pragma unroll
            for (int i = 0; i < 4; ++i)
#pragma unroll
                for (int j = 0; j < 2; ++j)
                    acc[i][j] = MFMA64(a[i], bfr[j], acc[i][j]);
        }
    }

    // epilogue: D-mapping selected by fm (identical to v5)
#pragma unroll
    for (int j = 0; j < 2; ++j)
#pragma unroll
        for (int i = 0; i < 4; ++i)
#pragma unroll
            for (int r = 0; r < 4; ++r) {
                int rin = (fm == 1) ? (4 * lk + r) : (fm == 2) ? lr
                        : (fm == 3) ? (lk + 4 * r) : lr;
                int cin = (fm == 1) ? lr : (fm == 2) ? (4 * lk + r)
                        : (fm == 3) ? lr : (lk + 4 * r);
                int row = m0 + wr * 64 + 16 * i + rin;
                int col = n0 + wc * 32 + 16 * j + cin;
                m1out[(size_t)row * H1_ + col] = acc[i][j][r] + (double)b1[col];
            }
#else
    (void)x; (void)W1; (void)b1; (void)m1out; (void)flag;
#endif
}

// ---------------------------------------------------------------------------
// Fallback VALU f64 GEMM (proven). Runs iff flag not in {1..4}.
// ---------------------------------------------------------------------------
#define BM 128
#define BN 128
#define BK 8
__global__ __launch_bounds__(256) void k_gemm1(const float* __restrict__ x,
                                               const float* __restrict__ W1,
                                               const float* __restrict__ b1,
                                               double* __restrict__ m1out,
                                               const int* __restrict__ flag) {
    int fm = flag[0];
    if (fm >= 1 && fm <= 4) return;
    __shared__ double As[BK][BM + 4];
    __shared__ double Bs[BK][BN + 4];

    int tid = threadIdx.x;
    int m0 = blockIdx.x * BM;
    int n0 = blockIdx.y * BN;
    int tx = tid & 15;
    int ty = tid >> 4;
    int lr = tid >> 1;
    int lk = (tid & 1) * 4;

    double acc[8][8] = {};

    for (int k0 = 0; k0 < D_; k0 += BK) {
        float4 av = *(const float4*)&x [(size_t)(m0 + lr) * D_ + k0 + lk];
        float4 bv = *(const float4*)&W1[(size_t)(n0 + lr) * D_ + k0 + lk];
        __syncthreads();
        As[lk + 0][lr] = (double)av.x;
        As[lk + 1][lr] = (double)av.y;
        As[lk + 2][lr] = (double)av.z;
        As[lk + 3][lr] = (double)av.w;
        Bs[lk + 0][lr] = (double)bv.x;
        Bs[lk + 1][lr] = (double)bv.y;
        Bs[lk + 2][lr] = (double)bv.z;
        Bs[lk + 3][lr] = (double)bv.w;
        __syncthreads();
#pragma unroll
        for (int kk = 0; kk < BK; ++kk) {
            double a[8], b[8];
#pragma unroll
            for (int i = 0; i < 8; ++i) a[i] = As[kk][tx + 16 * i];
#pragma unroll
            for (int j = 0; j < 8; ++j) b[j] = Bs[kk][ty + 16 * j];
#pragma unroll
            for (int i = 0; i < 8; ++i)
#pragma unroll
                for (int j = 0; j < 8; ++j)
                    acc[i][j] += a[i] * b[j];
        }
    }
#pragma unroll
    for (int j = 0; j < 8; ++j) {
        double bj = (double)b1[n0 + ty + 16 * j];
#pragma unroll
        for (int i = 0; i < 8; ++i) {
            m1out[(size_t)(m0 + tx + 16 * i) * H1_ + (n0 + ty + 16 * j)] =
                acc[i][j] + bj;
        }
    }
}

// ---------------------------------------------------------------------------
// Persistent per-sample SNN v4 (unchanged from R7, ~135 µs).
// ---------------------------------------------------------------------------
__global__ __launch_bounds__(256) void k_snn(const double* __restrict__ m1_0,
                                             const float* __restrict__ b1,
                                             const float* __restrict__ W1T,
                                             const float* __restrict__ W2T,
                                             const float* __restrict__ b2,
                                             const float* __restrict__ Wo,
                                             const float* __restrict__ bo,
                                             const int* __restrict__ nsteps_p,
                                             float* __restrict__ out) {
    __shared__ __align__(16) double pjbuf[H2_];      // 8 KB; aliased as l1idx
    __shared__ __align__(16) int l2idx[H2_];         // 4 KB
    __shared__ unsigned long long s1by[32];          // 256 B
    __shared__ unsigned long long s2nb[32];          // 256 B
    __shared__ int ncnt[2];
    __shared__ int anyb1[4], anyb2[4];

    int* l1idx = (int*)pjbuf;

    int b = blockIdx.x;
    int tid = threadIdx.x;
    int lane = tid & 63;
    int wv = tid >> 6;
    int T = nsteps_p[0];

    double m1r[8], m2r[4];
    float b1f[8], b2f[4];
    int cnt[4];

    const double* m1p = m1_0 + (size_t)b * H1_ + 8 * tid;
    {
        double2 v0 = *(const double2*)(m1p + 0);
        double2 v1 = *(const double2*)(m1p + 2);
        double2 v2 = *(const double2*)(m1p + 4);
        double2 v3 = *(const double2*)(m1p + 6);
        m1r[0] = v0.x; m1r[1] = v0.y; m1r[2] = v1.x; m1r[3] = v1.y;
        m1r[4] = v2.x; m1r[5] = v2.y; m1r[6] = v3.x; m1r[7] = v3.y;
    }
    {
        float4 f0 = *(const float4*)(b1 + 8 * tid);
        float4 f1 = *(const float4*)(b1 + 8 * tid + 4);
        b1f[0] = f0.x; b1f[1] = f0.y; b1f[2] = f0.z; b1f[3] = f0.w;
        b1f[4] = f1.x; b1f[5] = f1.y; b1f[6] = f1.z; b1f[7] = f1.w;
        float4 f2 = *(const float4*)(b2 + 4 * tid);
        b2f[0] = f2.x; b2f[1] = f2.y; b2f[2] = f2.z; b2f[3] = f2.w;
    }
#pragma unroll
    for (int q = 0; q < 4; ++q) { m2r[q] = 0.0; cnt[q] = 0; }

    int anyS2 = 0;

#define ACC2(v) { m2r[0] += (double)(v).x; m2r[1] += (double)(v).y; \
                  m2r[2] += (double)(v).z; m2r[3] += (double)(v).w; }

    for (int t = 0; t < T; ++t) {
        if (t > 0) {
#pragma unroll
            for (int q = 0; q < 8; ++q)
                m1r[q] = 0.9 * m1r[q] - (m1r[q] > 1.0 ? 1.0 : 0.0) + (double)b1f[q];
            if (anyS2) {
                int n2 = ncnt[1];
                const char* Wc = (const char*)W1T;
                size_t toff = (size_t)tid << 5;
                for (int k2 = 0; k2 < n2; ++k2) {
                    const float4* c4 = (const float4*)(Wc + l2idx[k2] + toff);
                    float4 va = c4[0];
                    float4 vb = c4[1];
                    m1r[0] += (double)va.x; m1r[1] += (double)va.y;
                    m1r[2] += (double)va.z; m1r[3] += (double)va.w;
                    m1r[4] += (double)vb.x; m1r[5] += (double)vb.y;
                    m1r[6] += (double)vb.z; m1r[7] += (double)vb.w;
                }
            }
        }
        unsigned bflag = 0;
#pragma unroll
        for (int q = 0; q < 8; ++q) bflag |= (m1r[q] > 1.0 ? 1u : 0u) << q;
        ((unsigned char*)s1by)[tid] = (unsigned char)bflag;
        {
            int wa = __any((int)bflag);
            if (lane == 0) anyb1[wv] = wa;
        }
#pragma unroll
        for (int q = 0; q < 4; ++q)
            m2r[q] = 0.9 * m2r[q] - (m2r[q] > 1.0 ? 1.0 : 0.0) + (double)b2f[q];
        {
            unsigned nib = 0;
#pragma unroll
            for (int q = 0; q < 4; ++q) nib |= (m2r[q] > 1.0 ? 1u : 0u) << q;
            ((unsigned char*)s2nb)[tid] = (unsigned char)nib;
            int wa = __any((int)nib);
            if (lane == 0) anyb2[wv] = wa;
        }
        __syncthreads();                                   // A
        int any1 = anyb1[0] | anyb1[1] | anyb1[2] | anyb1[3];
        if (any1) {
            if (tid < 64) {
                unsigned long long bits = (tid < 32) ? s1by[tid] : 0ULL;
                int pc = __popcll(bits);
                int sc = pc;
#pragma unroll
                for (int d = 1; d < 64; d <<= 1) {
                    int o = __shfl_up(sc, d);
                    if (tid >= d) sc += o;
                }
                if (tid == 63) ncnt[0] = sc;
                int off = sc - pc;
                int base = tid << 6;
                while (bits) {
                    l1idx[off++] = (base + __builtin_ctzll(bits)) << 12;
                    bits &= bits - 1;
                }
            }
            __syncthreads();                               // B
            {
                int n1 = ncnt[0];
                const char* Wc = (const char*)W2T;
                size_t toff = (size_t)tid << 4;
                int k = 0;
                for (; k + 8 <= n1; k += 8) {
                    int4 oa = *(const int4*)&l1idx[k];
                    int4 ob = *(const int4*)&l1idx[k + 4];
                    float4 v0 = *(const float4*)(Wc + oa.x + toff);
                    float4 v1 = *(const float4*)(Wc + oa.y + toff);
                    float4 v2 = *(const float4*)(Wc + oa.z + toff);
                    float4 v3 = *(const float4*)(Wc + oa.w + toff);
                    float4 v4 = *(const float4*)(Wc + ob.x + toff);
                    float4 v5 = *(const float4*)(Wc + ob.y + toff);
                    float4 v6 = *(const float4*)(Wc + ob.z + toff);
                    float4 v7 = *(const float4*)(Wc + ob.w + toff);
                    ACC2(v0); ACC2(v1); ACC2(v2); ACC2(v3);
                    ACC2(v4); ACC2(v5); ACC2(v6); ACC2(v7);
                }
                for (; k < n1; ++k) {
                    float4 v = *(const float4*)(Wc + l1idx[k] + toff);
                    ACC2(v);
                }
            }
            {
                unsigned nib = 0;
#pragma unroll
                for (int q = 0; q < 4; ++q) nib |= (m2r[q] > 1.0 ? 1u : 0u) << q;
                ((unsigned char*)s2nb)[tid] = (unsigned char)nib;
                int wa = __any((int)nib);
                if (lane == 0) anyb2[wv] = wa;
            }
            __syncthreads();                               // C
        }
        anyS2 = anyb2[0] | anyb2[1] | anyb2[2] | anyb2[3];
#pragma unroll
        for (int q = 0; q < 4; ++q) cnt[q] += (m2r[q] > 1.0) ? 1 : 0;
        if (anyS2) {
            if (tid < 64) {
                unsigned long long wbits = 0ULL;
                if (tid < 16) {
                    unsigned long long w0 = s2nb[2 * tid];
                    unsigned long long w1 = s2nb[2 * tid + 1];
                    w0 &= 0x0F0F0F0F0F0F0F0FULL;
                    w0 = (w0 | (w0 >> 4)) & 0x00FF00FF00FF00FFULL;
                    w0 = (w0 | (w0 >> 8)) & 0x0000FFFF0000FFFFULL;
                    w0 = (w0 | (w0 >> 16)) & 0x00000000FFFFFFFFULL;
                    w1 &= 0x0F0F0F0F0F0F0F0FULL;
                    w1 = (w1 | (w1 >> 4)) & 0x00FF00FF00FF00FFULL;
                    w1 = (w1 | (w1 >> 8)) & 0x0000FFFF0000FFFFULL;
                    w1 = (w1 | (w1 >> 16)) & 0x00000000FFFFFFFFULL;
                    wbits = w0 | (w1 << 32);
                }
                int pc = __popcll(wbits);
                int sc = pc;
#pragma unroll
                for (int d = 1; d < 64; d <<= 1) {
                    int o = __shfl_up(sc, d);
                    if (tid >= d) sc += o;
                }
                if (tid == 63) ncnt[1] = sc;
                int off = sc - pc;
                int base = tid << 6;
                while (wbits) {
                    l2idx[off++] = (base + __builtin_ctzll(wbits)) << 13;
                    wbits &= wbits - 1;
                }
            }
            __syncthreads();                               // D
        }
    }
#undef ACC2

    // ---- sparse epilogue ----
    __syncthreads();
#pragma unroll
    for (int q = 0; q < 4; ++q)
        pjbuf[4 * tid + q] = (double)cnt[q] / (double)T;
    {
        unsigned nib = 0;
#pragma unroll
        for (int q = 0; q < 4; ++q) nib |= (cnt[q] > 0 ? 1u : 0u) << q;
        ((unsigned char*)s2nb)[tid] = (unsigned char)nib;
    }
    __syncthreads();
    if (tid < 64) {
        unsigned long long wbits = 0ULL;
        if (tid < 16) {
            unsigned long long w0 = s2nb[2 * tid];
            unsigned long long w1 = s2nb[2 * tid + 1];
            w0 &= 0x0F0F0F0F0F0F0F0FULL;
            w0 = (w0 | (w0 >> 4)) & 0x00FF00FF00FF00FFULL;
            w0 = (w0 | (w0 >> 8)) & 0x0000FFFF0000FFFFULL;
            w0 = (w0 | (w0 >> 16)) & 0x00000000FFFFFFFFULL;
            w1 &= 0x0F0F0F0F0F0F0F0FULL;
            w1 = (w1 | (w1 >> 4)) & 0x00FF00FF00FF00FFULL;
            w1 = (w1 | (w1 >> 8)) & 0x0000FFFF0000FFFFULL;
            w1 = (w1 | (w1 >> 16)) & 0x00000000FFFFFFFFULL;
            wbits = w0 | (w1 << 32);
        }
        int pc = __popcll(wbits);
        int sc = pc;
#pragma unroll
        for (int d = 1; d < 64; d <<= 1) {
            int o = __shfl_up(sc, d);
            if (tid >= d) sc += o;
        }
        if (tid == 63) ncnt[1] = sc;
        int off = sc - pc;
        int base = tid << 6;
        while (wbits) {
            l2idx[off++] = base + __builtin_ctzll(wbits);
            wbits &= wbits - 1;
        }
    }
    __syncthreads();
    if (tid < C_) {
        int c = tid;
        int na = ncnt[1];
        const float* worow = &Wo[(size_t)c * H2_];
        double acc = 0.0;
        for (int k = 0; k < na; ++k) {
            int j = l2idx[k];
            acc += pjbuf[j] * (double)worow[j];
        }
        out[(size_t)b * C_ + c] = (float)(acc + (double)bo[c]);
    }
}

// ---------------------------------------------------------------------------
extern "C" void kernel_launch(void* const* d_in, const int* in_sizes, int n_in,
                              void* d_out, int out_size, void* d_ws, size_t ws_size,
                              hipStream_t stream) {
    const float* x  = (const float*)d_in[0];   // [4096,1024]
    const float* W1 = (const float*)d_in[1];   // [2048,1024]
    const float* b1 = (const float*)d_in[2];   // [2048]
    const float* W2 = (const float*)d_in[3];   // [1024,2048]
    const float* b2 = (const float*)d_in[4];   // [1024]
    const float* Wo = (const float*)d_in[5];   // [64,1024]
    const float* bo = (const float*)d_in[6];   // [64]
    const int* nst  = (const int*)d_in[7];     // [1] = 20
    float* out = (float*)d_out;

    size_t off_m1   = 0;                                   // f64 [4096][2048]
    size_t off_w1t  = off_m1 + (size_t)B_ * H1_ * 8;
    size_t off_w2t  = off_w1t + (size_t)D_ * H1_ * 4;
    size_t off_flag = off_w2t + (size_t)H1_ * H2_ * 4;
    size_t need     = off_flag + 64;
    if (ws_size < need) return;

    double* m1ws = (double*)((char*)d_ws + off_m1);
    float*  W1T  = (float*)((char*)d_ws + off_w1t);
    float*  W2T  = (float*)((char*)d_ws + off_w2t);
    int*    flag = (int*)((char*)d_ws + off_flag);

    k_probe<<<1, 64, 0, stream>>>(flag);

    k_transpose<<<dim3(D_ / 32, H1_ / 32), dim3(32, 8), 0, stream>>>(W1, W1T, H1_, D_);
    k_transpose<<<dim3(H1_ / 32, H2_ / 32), dim3(32, 8), 0, stream>>>(W2, W2T, H2_, H1_);

    k_gemm_mfma<<<dim3(B_ / GBM, H1_ / GBN), 512, 0, stream>>>(x, W1, b1, m1ws, flag);
    k_gemm1<<<dim3(B_ / BM, H1_ / BN), 256, 0, stream>>>(x, W1, b1, m1ws, flag);

    k_snn<<<B_, 256, 0, stream>>>(m1ws, b1, W1T, W2T, b2, Wo, bo, nst, out);
}

// Round 14
// 440.388 us; speedup vs baseline: 1.0244x; 1.0012x over previous
//
#include <hip/hip_runtime.h>
#include <hip/hip_bf16.h>

// Sizes (fixed by the reference): B=4096, D=1024, H1=2048, H2=1024, C=64, T=20
#define B_   4096
#define D_   1024
#define H1_  2048
#define H2_  1024
#define C_   64

typedef double d4 __attribute__((ext_vector_type(4)));

#if defined(__has_builtin)
#  if __has_builtin(__builtin_amdgcn_mfma_f64_16x16x4f64)
#    define MFMA64(A, B, C) __builtin_amdgcn_mfma_f64_16x16x4f64((A), (B), (C), 0, 0, 0)
#    define HAVE_MFMA64 1
#  elif __has_builtin(__builtin_amdgcn_mfma_f64_16x16x4_f64)
#    define MFMA64(A, B, C) __builtin_amdgcn_mfma_f64_16x16x4_f64((A), (B), (C), 0, 0, 0)
#    define HAVE_MFMA64 1
#  endif
#endif

// ---------------------------------------------------------------------------
// Probe: discover v_mfma_f64_16x16x4 D-fragment layout at runtime.
// ---------------------------------------------------------------------------
__global__ void k_probe(int* flag) {
#if defined(HAVE_MFMA64)
    int lane = threadIdx.x & 63;
    int lr = lane & 15, lk = lane >> 4;
    double a  = (double)(5 * lr + 3 * lk + 1);    // A[r][k] = 5r+3k+1
    double bb = (double)(11 * lk + 2 * lr + 2);   // B[k][c] = 11k+2c+2
    d4 c = {0.0, 0.0, 0.0, 0.0};
    c = MFMA64(a, bb, c);
    int okm[4] = {1, 1, 1, 1};
#pragma unroll
    for (int j = 0; j < 4; ++j) {
        double e1 = 0, e2 = 0, e3 = 0, e4 = 0;
        for (int k = 0; k < 4; ++k) {
            e1 += (double)(5 * (4 * lk + j) + 3 * k + 1) * (double)(11 * k + 2 * lr + 2);
            e2 += (double)(5 * lr + 3 * k + 1) * (double)(11 * k + 2 * (4 * lk + j) + 2);
            e3 += (double)(5 * (lk + 4 * j) + 3 * k + 1) * (double)(11 * k + 2 * lr + 2);
            e4 += (double)(5 * lr + 3 * k + 1) * (double)(11 * k + 2 * (lk + 4 * j) + 2);
        }
        if (c[j] != e1) okm[0] = 0;
        if (c[j] != e2) okm[1] = 0;
        if (c[j] != e3) okm[2] = 0;
        if (c[j] != e4) okm[3] = 0;
    }
    int f = 0;
    for (int m = 3; m >= 0; --m) {
        unsigned long long all = __ballot(okm[m] != 0);
        if (all == ~0ULL) f = m + 1;
    }
    if (lane == 0) flag[0] = f;
#else
    if ((threadIdx.x & 63) == 0) flag[0] = 0;
#endif
}

// ---------------------------------------------------------------------------
// Transpose: out[c][r] = in[r][c]   (f32, 32x32 LDS tiles)
// ---------------------------------------------------------------------------
__global__ __launch_bounds__(256) void k_transpose(const float* __restrict__ in,
                                                   float* __restrict__ out,
                                                   int R, int C) {
    __shared__ float t[32][33];
    int c0 = blockIdx.x * 32;
    int r0 = blockIdx.y * 32;
    int lx = threadIdx.x;
    int ly = threadIdx.y;
#pragma unroll
    for (int q = 0; q < 4; ++q) {
        int rr = ly + 8 * q;
        t[rr][lx] = in[(size_t)(r0 + rr) * C + (c0 + lx)];
    }
    __syncthreads();
#pragma unroll
    for (int q = 0; q < 4; ++q) {
        int cc = ly + 8 * q;
        out[(size_t)(c0 + cc) * R + (r0 + lx)] = t[lx][cc];
    }
}

// ---------------------------------------------------------------------------
// f64 MFMA GEMM v9: v8 (tile 128x128, GBK=64, 512 thr, wave-tile 64x32,
// f32 LDS, conflict-free pad) + ANTI-PHASE k-loop rotation:
// block processes k-tiles in order (t + ph) & 15, ph = 8*((bx+by)&1), so
// co-resident blocks are half-a-loop out of phase -> one block's MFMA
// covers the other's barrier drain.
// f64 accumulation order rotates (not bit-identical to v8), but output
// depends only on integer spike counts; flip prob ~4e-7 -> absmax stays 0.
// ---------------------------------------------------------------------------
#define GBM 128
#define GBN 128
#define GBK 64
#define NKT (D_ / GBK)   // 16 k-tiles
#define ASZ32 8832       // AIDX32(63,127)+1 = 8824, rounded up
__device__ __forceinline__ int AIDX32(int k, int r) {
    return k * 136 + ((k >> 2) << 3) + ((k & 1) << 3) + r;
}
__global__ __launch_bounds__(512, 4) void k_gemm_mfma(const float* __restrict__ x,
                                                      const float* __restrict__ W1,
                                                      const float* __restrict__ b1,
                                                      double* __restrict__ m1out,
                                                      const int* __restrict__ flag) {
#if defined(HAVE_MFMA64)
    int fm = flag[0];
    if (fm < 1 || fm > 4) return;
    __shared__ float As[ASZ32];   // 34.5 KB
    __shared__ float Bs[ASZ32];   // 34.5 KB  (69 KB -> 2 blocks/CU)

    int tid = threadIdx.x;
    int m0 = blockIdx.x * GBM;
    int n0 = blockIdx.y * GBN;
    int ph = ((blockIdx.x + blockIdx.y) & 1) * (NKT / 2);   // anti-phase offset
    int w = tid >> 6, lane = tid & 63;
    int wr = w >> 2;        // 0..1 : 64-row half
    int wc = w & 3;         // 0..3 : 32-col quarter
    int lr = lane & 15, lk = lane >> 4;

    int srow = tid >> 2;           // 0..127
    int g    = tid & 3;            // k sub-group
    int woff = AIDX32(4 * g, srow);   // in-group offsets {0,144,272,416}; +16k: +2208

    const float* xrow = x  + (size_t)(m0 + srow) * D_;
    const float* wrow = W1 + (size_t)(n0 + srow) * D_;

    d4 acc[4][2];
#pragma unroll
    for (int i = 0; i < 4; ++i)
#pragma unroll
        for (int j = 0; j < 2; ++j) acc[i][j] = (d4){0.0, 0.0, 0.0, 0.0};

    for (int t = 0; t < NKT; ++t) {
        int k0 = (((t + ph) & (NKT - 1))) * GBK;
        float4 av[4], bv[4];
#pragma unroll
        for (int q = 0; q < 4; ++q) {
            av[q] = *(const float4*)&xrow[k0 + 4 * g + 16 * q];
            bv[q] = *(const float4*)&wrow[k0 + 4 * g + 16 * q];
        }
        __syncthreads();   // all fragment reads of previous tile complete
#pragma unroll
        for (int q = 0; q < 4; ++q) {
            int o = woff + q * 2208;
            As[o +   0] = av[q].x;
            As[o + 144] = av[q].y;
            As[o + 272] = av[q].z;
            As[o + 416] = av[q].w;
            Bs[o +   0] = bv[q].x;
            Bs[o + 144] = bv[q].y;
            Bs[o + 272] = bv[q].z;
            Bs[o + 416] = bv[q].w;
        }
        __syncthreads();   // tile staged
#pragma unroll
        for (int kb = 0; kb < 16; ++kb) {
            int k = kb * 4 + lk;
            int abase = AIDX32(k, wr * 64 + lr);
            int bbase = AIDX32(k, wc * 32 + lr);
            double a[4], bfr[2];
#pragma unroll
            for (int i = 0; i < 4; ++i) a[i]   = (double)As[abase + 16 * i];
#pragma unroll
            for (int j = 0; j < 2; ++j) bfr[j] = (double)Bs[bbase + 16 * j];
#pragma unroll
            for (int i = 0; i < 4; ++i)
#pragma unroll
                for (int j = 0; j < 2; ++j)
                    acc[i][j] = MFMA64(a[i], bfr[j], acc[i][j]);
        }
    }

    // epilogue: D-mapping selected by fm
#pragma unroll
    for (int j = 0; j < 2; ++j)
#pragma unroll
        for (int i = 0; i < 4; ++i)
#pragma unroll
            for (int r = 0; r < 4; ++r) {
                int rin = (fm == 1) ? (4 * lk + r) : (fm == 2) ? lr
                        : (fm == 3) ? (lk + 4 * r) : lr;
                int cin = (fm == 1) ? lr : (fm == 2) ? (4 * lk + r)
                        : (fm == 3) ? lr : (lk + 4 * r);
                int row = m0 + wr * 64 + 16 * i + rin;
                int col = n0 + wc * 32 + 16 * j + cin;
                m1out[(size_t)row * H1_ + col] = acc[i][j][r] + (double)b1[col];
            }
#else
    (void)x; (void)W1; (void)b1; (void)m1out; (void)flag;
#endif
}

// ---------------------------------------------------------------------------
// Fallback VALU f64 GEMM (proven). Runs iff flag not in {1..4}.
// ---------------------------------------------------------------------------
#define BM 128
#define BN 128
#define BK 8
__global__ __launch_bounds__(256) void k_gemm1(const float* __restrict__ x,
                                               const float* __restrict__ W1,
                                               const float* __restrict__ b1,
                                               double* __restrict__ m1out,
                                               const int* __restrict__ flag) {
    int fm = flag[0];
    if (fm >= 1 && fm <= 4) return;
    __shared__ double As[BK][BM + 4];
    __shared__ double Bs[BK][BN + 4];

    int tid = threadIdx.x;
    int m0 = blockIdx.x * BM;
    int n0 = blockIdx.y * BN;
    int tx = tid & 15;
    int ty = tid >> 4;
    int lr = tid >> 1;
    int lk = (tid & 1) * 4;

    double acc[8][8] = {};

    for (int k0 = 0; k0 < D_; k0 += BK) {
        float4 av = *(const float4*)&x [(size_t)(m0 + lr) * D_ + k0 + lk];
        float4 bv = *(const float4*)&W1[(size_t)(n0 + lr) * D_ + k0 + lk];
        __syncthreads();
        As[lk + 0][lr] = (double)av.x;
        As[lk + 1][lr] = (double)av.y;
        As[lk + 2][lr] = (double)av.z;
        As[lk + 3][lr] = (double)av.w;
        Bs[lk + 0][lr] = (double)bv.x;
        Bs[lk + 1][lr] = (double)bv.y;
        Bs[lk + 2][lr] = (double)bv.z;
        Bs[lk + 3][lr] = (double)bv.w;
        __syncthreads();
#pragma unroll
        for (int kk = 0; kk < BK; ++kk) {
            double a[8], b[8];
#pragma unroll
            for (int i = 0; i < 8; ++i) a[i] = As[kk][tx + 16 * i];
#pragma unroll
            for (int j = 0; j < 8; ++j) b[j] = Bs[kk][ty + 16 * j];
#pragma unroll
            for (int i = 0; i < 8; ++i)
#pragma unroll
                for (int j = 0; j < 8; ++j)
                    acc[i][j] += a[i] * b[j];
        }
    }
#pragma unroll
    for (int j = 0; j < 8; ++j) {
        double bj = (double)b1[n0 + ty + 16 * j];
#pragma unroll
        for (int i = 0; i < 8; ++i) {
            m1out[(size_t)(m0 + tx + 16 * i) * H1_ + (n0 + ty + 16 * j)] =
                acc[i][j] + bj;
        }
    }
}

// ---------------------------------------------------------------------------
// Persistent per-sample SNN v4 (unchanged from R7, ~135 µs).
// ---------------------------------------------------------------------------
__global__ __launch_bounds__(256) void k_snn(const double* __restrict__ m1_0,
                                             const float* __restrict__ b1,
                                             const float* __restrict__ W1T,
                                             const float* __restrict__ W2T,
                                             const float* __restrict__ b2,
                                             const float* __restrict__ Wo,
                                             const float* __restrict__ bo,
                                             const int* __restrict__ nsteps_p,
                                             float* __restrict__ out) {
    __shared__ __align__(16) double pjbuf[H2_];      // 8 KB; aliased as l1idx
    __shared__ __align__(16) int l2idx[H2_];         // 4 KB
    __shared__ unsigned long long s1by[32];          // 256 B
    __shared__ unsigned long long s2nb[32];          // 256 B
    __shared__ int ncnt[2];
    __shared__ int anyb1[4], anyb2[4];

    int* l1idx = (int*)pjbuf;

    int b = blockIdx.x;
    int tid = threadIdx.x;
    int lane = tid & 63;
    int wv = tid >> 6;
    int T = nsteps_p[0];

    double m1r[8], m2r[4];
    float b1f[8], b2f[4];
    int cnt[4];

    const double* m1p = m1_0 + (size_t)b * H1_ + 8 * tid;
    {
        double2 v0 = *(const double2*)(m1p + 0);
        double2 v1 = *(const double2*)(m1p + 2);
        double2 v2 = *(const double2*)(m1p + 4);
        double2 v3 = *(const double2*)(m1p + 6);
        m1r[0] = v0.x; m1r[1] = v0.y; m1r[2] = v1.x; m1r[3] = v1.y;
        m1r[4] = v2.x; m1r[5] = v2.y; m1r[6] = v3.x; m1r[7] = v3.y;
    }
    {
        float4 f0 = *(const float4*)(b1 + 8 * tid);
        float4 f1 = *(const float4*)(b1 + 8 * tid + 4);
        b1f[0] = f0.x; b1f[1] = f0.y; b1f[2] = f0.z; b1f[3] = f0.w;
        b1f[4] = f1.x; b1f[5] = f1.y; b1f[6] = f1.z; b1f[7] = f1.w;
        float4 f2 = *(const float4*)(b2 + 4 * tid);
        b2f[0] = f2.x; b2f[1] = f2.y; b2f[2] = f2.z; b2f[3] = f2.w;
    }
#pragma unroll
    for (int q = 0; q < 4; ++q) { m2r[q] = 0.0; cnt[q] = 0; }

    int anyS2 = 0;

#define ACC2(v) { m2r[0] += (double)(v).x; m2r[1] += (double)(v).y; \
                  m2r[2] += (double)(v).z; m2r[3] += (double)(v).w; }

    for (int t = 0; t < T; ++t) {
        if (t > 0) {
#pragma unroll
            for (int q = 0; q < 8; ++q)
                m1r[q] = 0.9 * m1r[q] - (m1r[q] > 1.0 ? 1.0 : 0.0) + (double)b1f[q];
            if (anyS2) {
                int n2 = ncnt[1];
                const char* Wc = (const char*)W1T;
                size_t toff = (size_t)tid << 5;
                for (int k2 = 0; k2 < n2; ++k2) {
                    const float4* c4 = (const float4*)(Wc + l2idx[k2] + toff);
                    float4 va = c4[0];
                    float4 vb = c4[1];
                    m1r[0] += (double)va.x; m1r[1] += (double)va.y;
                    m1r[2] += (double)va.z; m1r[3] += (double)va.w;
                    m1r[4] += (double)vb.x; m1r[5] += (double)vb.y;
                    m1r[6] += (double)vb.z; m1r[7] += (double)vb.w;
                }
            }
        }
        unsigned bflag = 0;
#pragma unroll
        for (int q = 0; q < 8; ++q) bflag |= (m1r[q] > 1.0 ? 1u : 0u) << q;
        ((unsigned char*)s1by)[tid] = (unsigned char)bflag;
        {
            int wa = __any((int)bflag);
            if (lane == 0) anyb1[wv] = wa;
        }
#pragma unroll
        for (int q = 0; q < 4; ++q)
            m2r[q] = 0.9 * m2r[q] - (m2r[q] > 1.0 ? 1.0 : 0.0) + (double)b2f[q];
        {
            unsigned nib = 0;
#pragma unroll
            for (int q = 0; q < 4; ++q) nib |= (m2r[q] > 1.0 ? 1u : 0u) << q;
            ((unsigned char*)s2nb)[tid] = (unsigned char)nib;
            int wa = __any((int)nib);
            if (lane == 0) anyb2[wv] = wa;
        }
        __syncthreads();                                   // A
        int any1 = anyb1[0] | anyb1[1] | anyb1[2] | anyb1[3];
        if (any1) {
            if (tid < 64) {
                unsigned long long bits = (tid < 32) ? s1by[tid] : 0ULL;
                int pc = __popcll(bits);
                int sc = pc;
#pragma unroll
                for (int d = 1; d < 64; d <<= 1) {
                    int o = __shfl_up(sc, d);
                    if (tid >= d) sc += o;
                }
                if (tid == 63) ncnt[0] = sc;
                int off = sc - pc;
                int base = tid << 6;
                while (bits) {
                    l1idx[off++] = (base + __builtin_ctzll(bits)) << 12;
                    bits &= bits - 1;
                }
            }
            __syncthreads();                               // B
            {
                int n1 = ncnt[0];
                const char* Wc = (const char*)W2T;
                size_t toff = (size_t)tid << 4;
                int k = 0;
                for (; k + 8 <= n1; k += 8) {
                    int4 oa = *(const int4*)&l1idx[k];
                    int4 ob = *(const int4*)&l1idx[k + 4];
                    float4 v0 = *(const float4*)(Wc + oa.x + toff);
                    float4 v1 = *(const float4*)(Wc + oa.y + toff);
                    float4 v2 = *(const float4*)(Wc + oa.z + toff);
                    float4 v3 = *(const float4*)(Wc + oa.w + toff);
                    float4 v4 = *(const float4*)(Wc + ob.x + toff);
                    float4 v5 = *(const float4*)(Wc + ob.y + toff);
                    float4 v6 = *(const float4*)(Wc + ob.z + toff);
                    float4 v7 = *(const float4*)(Wc + ob.w + toff);
                    ACC2(v0); ACC2(v1); ACC2(v2); ACC2(v3);
                    ACC2(v4); ACC2(v5); ACC2(v6); ACC2(v7);
                }
                for (; k < n1; ++k) {
                    float4 v = *(const float4*)(Wc + l1idx[k] + toff);
                    ACC2(v);
                }
            }
            {
                unsigned nib = 0;
#pragma unroll
                for (int q = 0; q < 4; ++q) nib |= (m2r[q] > 1.0 ? 1u : 0u) << q;
                ((unsigned char*)s2nb)[tid] = (unsigned char)nib;
                int wa = __any((int)nib);
                if (lane == 0) anyb2[wv] = wa;
            }
            __syncthreads();                               // C
        }
        anyS2 = anyb2[0] | anyb2[1] | anyb2[2] | anyb2[3];
#pragma unroll
        for (int q = 0; q < 4; ++q) cnt[q] += (m2r[q] > 1.0) ? 1 : 0;
        if (anyS2) {
            if (tid < 64) {
                unsigned long long wbits = 0ULL;
                if (tid < 16) {
                    unsigned long long w0 = s2nb[2 * tid];
                    unsigned long long w1 = s2nb[2 * tid + 1];
                    w0 &= 0x0F0F0F0F0F0F0F0FULL;
                    w0 = (w0 | (w0 >> 4)) & 0x00FF00FF00FF00FFULL;
                    w0 = (w0 | (w0 >> 8)) & 0x0000FFFF0000FFFFULL;
                    w0 = (w0 | (w0 >> 16)) & 0x00000000FFFFFFFFULL;
                    w1 &= 0x0F0F0F0F0F0F0F0FULL;
                    w1 = (w1 | (w1 >> 4)) & 0x00FF00FF00FF00FFULL;
                    w1 = (w1 | (w1 >> 8)) & 0x0000FFFF0000FFFFULL;
                    w1 = (w1 | (w1 >> 16)) & 0x00000000FFFFFFFFULL;
                    wbits = w0 | (w1 << 32);
                }
                int pc = __popcll(wbits);
                int sc = pc;
#pragma unroll
                for (int d = 1; d < 64; d <<= 1) {
                    int o = __shfl_up(sc, d);
                    if (tid >= d) sc += o;
                }
                if (tid == 63) ncnt[1] = sc;
                int off = sc - pc;
                int base = tid << 6;
                while (wbits) {
                    l2idx[off++] = (base + __builtin_ctzll(wbits)) << 13;
                    wbits &= wbits - 1;
                }
            }
            __syncthreads();                               // D
        }
    }
#undef ACC2

    // ---- sparse epilogue ----
    __syncthreads();
#pragma unroll
    for (int q = 0; q < 4; ++q)
        pjbuf[4 * tid + q] = (double)cnt[q] / (double)T;
    {
        unsigned nib = 0;
#pragma unroll
        for (int q = 0; q < 4; ++q) nib |= (cnt[q] > 0 ? 1u : 0u) << q;
        ((unsigned char*)s2nb)[tid] = (unsigned char)nib;
    }
    __syncthreads();
    if (tid < 64) {
        unsigned long long wbits = 0ULL;
        if (tid < 16) {
            unsigned long long w0 = s2nb[2 * tid];
            unsigned long long w1 = s2nb[2 * tid + 1];
            w0 &= 0x0F0F0F0F0F0F0F0FULL;
            w0 = (w0 | (w0 >> 4)) & 0x00FF00FF00FF00FFULL;
            w0 = (w0 | (w0 >> 8)) & 0x0000FFFF0000FFFFULL;
            w0 = (w0 | (w0 >> 16)) & 0x00000000FFFFFFFFULL;
            w1 &= 0x0F0F0F0F0F0F0F0FULL;
            w1 = (w1 | (w1 >> 4)) & 0x00FF00FF00FF00FFULL;
            w1 = (w1 | (w1 >> 8)) & 0x0000FFFF0000FFFFULL;
            w1 = (w1 | (w1 >> 16)) & 0x00000000FFFFFFFFULL;
            wbits = w0 | (w1 << 32);
        }
        int pc = __popcll(wbits);
        int sc = pc;
#pragma unroll
        for (int d = 1; d < 64; d <<= 1) {
            int o = __shfl_up(sc, d);
            if (tid >= d) sc += o;
        }
        if (tid == 63) ncnt[1] = sc;
        int off = sc - pc;
        int base = tid << 6;
        while (wbits) {
            l2idx[off++] = base + __builtin_ctzll(wbits);
            wbits &= wbits - 1;
        }
    }
    __syncthreads();
    if (tid < C_) {
        int c = tid;
        int na = ncnt[1];
        const float* worow = &Wo[(size_t)c * H2_];
        double acc = 0.0;
        for (int k = 0; k < na; ++k) {
            int j = l2idx[k];
            acc += pjbuf[j] * (double)worow[j];
        }
        out[(size_t)b * C_ + c] = (float)(acc + (double)bo[c]);
    }
}

// ---------------------------------------------------------------------------
extern "C" void kernel_launch(void* const* d_in, const int* in_sizes, int n_in,
                              void* d_out, int out_size, void* d_ws, size_t ws_size,
                              hipStream_t stream) {
    const float* x  = (const float*)d_in[0];   // [4096,1024]
    const float* W1 = (const float*)d_in[1];   // [2048,1024]
    const float* b1 = (const float*)d_in[2];   // [2048]
    const float* W2 = (const float*)d_in[3];   // [1024,2048]
    const float* b2 = (const float*)d_in[4];   // [1024]
    const float* Wo = (const float*)d_in[5];   // [64,1024]
    const float* bo = (const float*)d_in[6];   // [64]
    const int* nst  = (const int*)d_in[7];     // [1] = 20
    float* out = (float*)d_out;

    size_t off_m1   = 0;                                   // f64 [4096][2048]
    size_t off_w1t  = off_m1 + (size_t)B_ * H1_ * 8;
    size_t off_w2t  = off_w1t + (size_t)D_ * H1_ * 4;
    size_t off_flag = off_w2t + (size_t)H1_ * H2_ * 4;
    size_t need     = off_flag + 64;
    if (ws_size < need) return;

    double* m1ws = (double*)((char*)d_ws + off_m1);
    float*  W1T  = (float*)((char*)d_ws + off_w1t);
    float*  W2T  = (float*)((char*)d_ws + off_w2t);
    int*    flag = (int*)((char*)d_ws + off_flag);

    k_probe<<<1, 64, 0, stream>>>(flag);

    k_transpose<<<dim3(D_ / 32, H1_ / 32), dim3(32, 8), 0, stream>>>(W1, W1T, H1_, D_);
    k_transpose<<<dim3(H1_ / 32, H2_ / 32), dim3(32, 8), 0, stream>>>(W2, W2T, H2_, H1_);

    k_gemm_mfma<<<dim3(B_ / GBM, H1_ / GBN), 512, 0, stream>>>(x, W1, b1, m1ws, flag);
    k_gemm1<<<dim3(B_ / BM, H1_ / BN), 256, 0, stream>>>(x, W1, b1, m1ws, flag);

    k_snn<<<B_, 256, 0, stream>>>(m1ws, b1, W1T, W2T, b2, Wo, bo, nst, out);
}